// Round 1
// baseline (570.392 us; speedup 1.0000x reference)
//
#include <hip/hip_runtime.h>
#include <stdint.h>

// VQ-VAE nearest-codebook index: N=32768 queries (32x1024), D=64, K=8192.
// score(n,k) = ||c_k||^2 - 2 * x_n . c_k   (argmin-equivalent to squared dist)
// fp32 register-tiled "GEMM + fused argmin". Split-K=2 for occupancy.

#define N_TOTAL 32768
#define K_CODES 8192
#define BM 128
#define BN 128
#define PAD 68   // 64 + 4 pad floats: bank = (4m + d) % 32 -> <=2-way (free)

// ---- codebook squared norms: 4 threads per row, shuffle-reduce ----
__global__ void vq_norms(const float4* __restrict__ cb, float* __restrict__ c2) {
    int t = blockIdx.x * 256 + threadIdx.x;     // 32768 threads, 8192 rows
    int r = t >> 2, p = t & 3;
    float s = 0.f;
#pragma unroll
    for (int i = 0; i < 4; ++i) {
        float4 v = cb[r * 16 + p * 4 + i];
        s += v.x * v.x + v.y * v.y + v.z * v.z + v.w * v.w;
    }
    s += __shfl_xor(s, 1);
    s += __shfl_xor(s, 2);
    if (p == 0) c2[r] = s;
}

// ---- main: one block = 128 queries x (K/ktPer-slice) codes ----
__global__ __launch_bounds__(256) void vq_main(
    const float4* __restrict__ lat, const float4* __restrict__ cb,
    const float* __restrict__ c2, int ktPer,
    int* __restrict__ outIdx, float* __restrict__ partS, int* __restrict__ partI,
    int writePartial) {
    __shared__ float As[BM][PAD];
    __shared__ float Bs[BN][PAD];
    __shared__ float c2s[BN];

    const int tid = threadIdx.x;
    const int tx = tid & 15;   // query group: m = tx + 16*ii
    const int ty = tid >> 4;   // code group:  k = ty + 16*jj
    const int nBase = blockIdx.x * BM;
    const int kt0 = blockIdx.y * ktPer;
    const int ktN = kt0 + ktPer;

    // Load A tile (128 x 64 floats), d-contiguous coalesced reads.
#pragma unroll
    for (int r = 0; r < 8; ++r) {
        int f = tid + 256 * r;          // 0..2047 float4s
        int m = f >> 4, d4 = f & 15;
        float4 v = lat[(size_t)(nBase + m) * 16 + d4];
        *(float4*)&As[m][d4 * 4] = v;
    }

    float best[8];
    int   bidx[8];
#pragma unroll
    for (int ii = 0; ii < 8; ++ii) { best[ii] = 1e30f; bidx[ii] = 0; }

    for (int kt = kt0; kt < ktN; ++kt) {
        const int kbase = kt * BN;
        __syncthreads();   // protect Bs from previous iteration's readers (also orders As first time)
#pragma unroll
        for (int r = 0; r < 8; ++r) {
            int f = tid + 256 * r;
            int k = f >> 4, d4 = f & 15;
            float4 v = cb[(size_t)(kbase + k) * 16 + d4];
            *(float4*)&Bs[k][d4 * 4] = v;
        }
        if (tid < BN) c2s[tid] = c2[kbase + tid];
        __syncthreads();

        float acc[8][8];
#pragma unroll
        for (int ii = 0; ii < 8; ++ii)
#pragma unroll
            for (int jj = 0; jj < 8; ++jj) acc[ii][jj] = 0.f;

#pragma unroll 4
        for (int d4 = 0; d4 < 16; ++d4) {
            float4 a[8], b[8];
#pragma unroll
            for (int ii = 0; ii < 8; ++ii)
                a[ii] = *(const float4*)&As[tx + 16 * ii][d4 * 4];
#pragma unroll
            for (int jj = 0; jj < 8; ++jj)
                b[jj] = *(const float4*)&Bs[ty + 16 * jj][d4 * 4];
#pragma unroll
            for (int ii = 0; ii < 8; ++ii)
#pragma unroll
                for (int jj = 0; jj < 8; ++jj)
                    acc[ii][jj] += a[ii].x * b[jj].x + a[ii].y * b[jj].y
                                 + a[ii].z * b[jj].z + a[ii].w * b[jj].w;
        }

        // fused argmin epilogue; jj ascending => k ascending per thread,
        // strict < keeps first (lowest-index) minimum.
#pragma unroll
        for (int jj = 0; jj < 8; ++jj) {
            int k = kbase + ty + 16 * jj;
            float cc = c2s[ty + 16 * jj];
#pragma unroll
            for (int ii = 0; ii < 8; ++ii) {
                float s = cc - 2.f * acc[ii][jj];
                if (s < best[ii]) { best[ii] = s; bidx[ii] = k; }
            }
        }
    }

    // cross-thread (ty) reduction per query via LDS (reusing As/Bs).
    __syncthreads();
    float* redS = &As[0][0];
    int*   redI = (int*)&Bs[0][0];
#pragma unroll
    for (int ii = 0; ii < 8; ++ii) {
        int m = tx + 16 * ii;
        redS[ty * BM + m] = best[ii];
        redI[ty * BM + m] = bidx[ii];
    }
    __syncthreads();
    if (tid < BM) {
        int m = tid;
        float bs = redS[m]; int bi = redI[m];
#pragma unroll
        for (int t = 1; t < 16; ++t) {
            float s = redS[t * BM + m]; int i = redI[t * BM + m];
            if (s < bs || (s == bs && i < bi)) { bs = s; bi = i; }
        }
        int n = nBase + m;
        if (writePartial) {
            partS[blockIdx.y * N_TOTAL + n] = bs;
            partI[blockIdx.y * N_TOTAL + n] = bi;
        } else {
            outIdx[n] = bi;
        }
    }
}

// ---- merge the two K-halves; tie -> half 0 (lower index) ----
__global__ void vq_merge(const float* __restrict__ partS, const int* __restrict__ partI,
                         int* __restrict__ out) {
    int n = blockIdx.x * 256 + threadIdx.x;
    float s0 = partS[n], s1 = partS[N_TOTAL + n];
    int   i0 = partI[n], i1 = partI[N_TOTAL + n];
    out[n] = (s1 < s0) ? i1 : i0;
}

extern "C" void kernel_launch(void* const* d_in, const int* in_sizes, int n_in,
                              void* d_out, int out_size, void* d_ws, size_t ws_size,
                              hipStream_t stream) {
    const float4* lat = (const float4*)d_in[0];   // (32,1024,64) fp32
    const float4* cb  = (const float4*)d_in[1];   // (8192,64) fp32
    int* out = (int*)d_out;                        // (32,1024) int32 indices

    float* c2 = (float*)d_ws;                                  // 8192 floats
    const size_t needSplit = (size_t)K_CODES * 4               // c2
                           + (size_t)2 * N_TOTAL * 4           // partS
                           + (size_t)2 * N_TOTAL * 4;          // partI

    vq_norms<<<128, 256, 0, stream>>>(cb, c2);

    if (ws_size >= needSplit) {
        float* partS = c2 + K_CODES;
        int*   partI = (int*)(partS + 2 * N_TOTAL);
        dim3 grid(N_TOTAL / BM, 2);
        vq_main<<<grid, 256, 0, stream>>>(lat, cb, c2, (K_CODES / BN) / 2,
                                          out, partS, partI, 1);
        vq_merge<<<N_TOTAL / 256, 256, 0, stream>>>(partS, partI, out);
    } else {
        dim3 grid(N_TOTAL / BM, 1);
        vq_main<<<grid, 256, 0, stream>>>(lat, cb, c2, K_CODES / BN,
                                          out, nullptr, nullptr, 0);
    }
}

// Round 2
// 367.099 us; speedup vs baseline: 1.5538x; 1.5538x over previous
//
#include <hip/hip_runtime.h>
#include <stdint.h>

// VQ-VAE nearest-codebook index: N=32768 queries, D=64, K=8192 codes.
// Phase A: bf16x3 MFMA (hi/lo split) computes approx scores, tracking per-query
//          best (s1,i1) and second-best (s2). Error-bounded by EPS_GAP.
// Phase B: queries with s2-s1 < EPS_GAP get exact fp32 recompute (matches the
//          validated round-1 math). Fallback to round-1 fp32 kernel if ws small.

#define N_TOTAL 32768
#define K_CODES 8192
#define EPS_GAP 0.0625f

typedef __attribute__((ext_vector_type(16))) float  floatx16;
typedef __attribute__((ext_vector_type(8)))  __bf16 bf16x8;

// ---- workspace layout (bytes) ----
#define O_C2    0u          // 8192 f32
#define O_CBSW  32768u      // [256 kBlk][16 cg][32 m][8 bf16] = 2 MB
#define O_LATSW 2129920u    // [1024 qBlk][16 cg][32 m][8 bf16] = 8 MB
#define O_PS1   10518528u   // 2*32768 f32
#define O_PS2   10780672u
#define O_PI1   11042816u
#define O_CNT   11304960u   // int count (+pad)
#define O_LIST  11305216u   // 32768 int
#define WS_NEED 11436288u

// ---- codebook squared norms (fp32, same as validated round 1) + zero counter
__global__ void vq_norms(const float4* __restrict__ cb, float* __restrict__ c2,
                         int* __restrict__ cnt) {
    if (blockIdx.x == 0 && threadIdx.x == 0) *cnt = 0;
    int t = blockIdx.x * 256 + threadIdx.x;
    int r = t >> 2, p = t & 3;
    float s = 0.f;
#pragma unroll
    for (int i = 0; i < 4; ++i) {
        float4 v = cb[r * 16 + p * 4 + i];
        s += v.x * v.x + v.y * v.y + v.z * v.z + v.w * v.w;
    }
    s += __shfl_xor(s, 1);
    s += __shfl_xor(s, 2);
    if (p == 0) c2[r] = s;
}

// ---- split fp32 rows into hi/lo bf16 in MFMA-fragment-friendly layout ----
// dst[rowBlk][cg][m][8]: cg 0..7 = hi d-group, 8..15 = lo d-group.
__global__ void vq_split(const float4* __restrict__ src, uint4* __restrict__ dst) {
    const int m = threadIdx.x & 31, g = threadIdx.x >> 5;
    const int rb = blockIdx.x;
    float4 a = src[(size_t)(rb * 32 + m) * 16 + g * 2];
    float4 b = src[(size_t)(rb * 32 + m) * 16 + g * 2 + 1];
    float x[8] = {a.x, a.y, a.z, a.w, b.x, b.y, b.z, b.w};
    bf16x8 hv, lv;
#pragma unroll
    for (int i = 0; i < 8; ++i) {
        float v  = x[i];
        __bf16 hb = (__bf16)v;           // RNE
        float r  = v - (float)hb;
        hv[i] = hb;
        lv[i] = (__bf16)r;
    }
    dst[(size_t)rb * 512 + g * 32 + m]       = __builtin_bit_cast(uint4, hv);
    dst[(size_t)rb * 512 + (8 + g) * 32 + m] = __builtin_bit_cast(uint4, lv);
}

// ---- phase A main: 128 queries x 4096 codes per block (split-K=2) ----
__global__ __launch_bounds__(256, 2) void vq_mfma(
    const uint4* __restrict__ latSw, const uint4* __restrict__ cbSw,
    const float* __restrict__ c2,
    float* __restrict__ pS1, float* __restrict__ pS2, int* __restrict__ pI1) {
    __shared__ uint4 As[2048];   // 32 KB: [4 wr][16 cg][32 m]
    __shared__ uint4 Bs[2048];   // 32 KB: [4 kb][16 cg][32 n]
    const int tid = threadIdx.x;
    const int wr = tid >> 6, lane = tid & 63;
    const int m = lane & 31, h = lane >> 5;

#pragma unroll
    for (int i = 0; i < 8; ++i)
        As[tid + 256 * i] = latSw[(size_t)blockIdx.x * 2048 + tid + 256 * i];
    __syncthreads();

    // A fragments resident in registers for the whole K loop (32 VGPRs).
    bf16x8 aH[4], aL[4];
#pragma unroll
    for (int c = 0; c < 4; ++c) {
        aH[c] = __builtin_bit_cast(bf16x8, As[wr * 512 + (c * 2 + h) * 32 + m]);
        aL[c] = __builtin_bit_cast(bf16x8, As[wr * 512 + (8 + c * 2 + h) * 32 + m]);
    }

    float s1[16], s2[16]; int i1[16];
#pragma unroll
    for (int r = 0; r < 16; ++r) { s1[r] = 3e38f; s2[r] = 3e38f; i1[r] = 0; }

    const int kBase = blockIdx.y * 4096;
    const uint4* cbBase = cbSw + (size_t)kBase * 16;

    for (int stage = 0; stage < 32; ++stage) {
        __syncthreads();
#pragma unroll
        for (int i = 0; i < 8; ++i)
            Bs[tid + 256 * i] = cbBase[(size_t)stage * 2048 + tid + 256 * i];
        __syncthreads();

#pragma unroll
        for (int kb = 0; kb < 4; ++kb) {
            const int col = kBase + stage * 128 + kb * 32 + m;
            const float cc = c2[col];
            floatx16 acc;
#pragma unroll
            for (int r = 0; r < 16; ++r) acc[r] = 0.f;
#pragma unroll
            for (int c = 0; c < 4; ++c) {
                bf16x8 bH = __builtin_bit_cast(bf16x8, Bs[kb * 512 + (c * 2 + h) * 32 + m]);
                bf16x8 bL = __builtin_bit_cast(bf16x8, Bs[kb * 512 + (8 + c * 2 + h) * 32 + m]);
                acc = __builtin_amdgcn_mfma_f32_32x32x16_bf16(aH[c], bH, acc, 0, 0, 0);
                acc = __builtin_amdgcn_mfma_f32_32x32x16_bf16(aL[c], bH, acc, 0, 0, 0);
                acc = __builtin_amdgcn_mfma_f32_32x32x16_bf16(aH[c], bL, acc, 0, 0, 0);
            }
            // fused argmin + second-best epilogue
#pragma unroll
            for (int r = 0; r < 16; ++r) {
                float s = fmaf(-2.f, acc[r], cc);
                s2[r] = fminf(s2[r], fmaxf(s, s1[r]));
                bool lt = s < s1[r];
                i1[r] = lt ? col : i1[r];
                s1[r] = lt ? s : s1[r];
            }
        }
    }

    // reduce (s1,i1,s2) across the 32 column-lanes of each half
#pragma unroll
    for (int mask = 1; mask <= 16; mask <<= 1) {
#pragma unroll
        for (int r = 0; r < 16; ++r) {
            float o1 = __shfl_xor(s1[r], mask);
            float o2 = __shfl_xor(s2[r], mask);
            int   oi = __shfl_xor(i1[r], mask);
            float n2 = fminf(fminf(s2[r], o2), fmaxf(s1[r], o1));
            bool take = (o1 < s1[r]) || (o1 == s1[r] && oi < i1[r]);
            s1[r] = take ? o1 : s1[r];
            i1[r] = take ? oi : i1[r];
            s2[r] = n2;
        }
    }

    if (m == 0) {
        const int qb = blockIdx.x * 128 + wr * 32;
        const int o0 = blockIdx.y * N_TOTAL;
#pragma unroll
        for (int r = 0; r < 16; ++r) {
            int row = (r & 3) + 8 * (r >> 2) + 4 * h;   // C/D layout row
            int q = qb + row;
            pS1[o0 + q] = s1[r];
            pS2[o0 + q] = s2[r];
            pI1[o0 + q] = i1[r];
        }
    }
}

// ---- merge split-K halves, write indices, flag near-ties ----
__global__ void vq_merge2(const float* __restrict__ pS1, const float* __restrict__ pS2,
                          const int* __restrict__ pI1, int* __restrict__ out,
                          int* __restrict__ cnt, int* __restrict__ list) {
    int q = blockIdx.x * 256 + threadIdx.x;
    float a1 = pS1[q],          a2 = pS2[q];          int ai = pI1[q];
    float b1 = pS1[N_TOTAL + q], b2 = pS2[N_TOTAL + q]; int bi = pI1[N_TOTAL + q];
    bool take = (b1 < a1) || (b1 == a1 && bi < ai);
    float s1 = take ? b1 : a1;
    int   i1 = take ? bi : ai;
    float s2 = fminf(fminf(a2, b2), fmaxf(a1, b1));
    out[q] = i1;
    if (s2 - s1 < EPS_GAP) {
        int slot = atomicAdd(cnt, 1);
        list[slot] = q;
    }
}

// ---- phase B: exact fp32 argmin for flagged queries (round-1 math) ----
__global__ __launch_bounds__(256) void vq_exact(
    const float4* __restrict__ lat, const float4* __restrict__ cb,
    const float* __restrict__ c2, const int* __restrict__ cnt,
    const int* __restrict__ list, int* __restrict__ out) {
    __shared__ float qv[64];
    __shared__ float rs[256];
    __shared__ int   ri[256];
    const int n = *cnt;
    for (int e = blockIdx.x; e < n; e += gridDim.x) {
        const int q = list[e];
        __syncthreads();
        if (threadIdx.x < 16) {
            float4 v = lat[(size_t)q * 16 + threadIdx.x];
            *(float4*)&qv[threadIdx.x * 4] = v;
        }
        __syncthreads();
        float best = 3e38f; int bi = 0;
        for (int k = threadIdx.x; k < K_CODES; k += 256) {
            float dot = 0.f;
#pragma unroll
            for (int d4 = 0; d4 < 16; ++d4) {
                float4 cv = cb[(size_t)k * 16 + d4];
                dot += qv[d4 * 4 + 0] * cv.x + qv[d4 * 4 + 1] * cv.y
                     + qv[d4 * 4 + 2] * cv.z + qv[d4 * 4 + 3] * cv.w;
            }
            float s = c2[k] - 2.f * dot;
            if (s < best) { best = s; bi = k; }
        }
        rs[threadIdx.x] = best; ri[threadIdx.x] = bi;
        __syncthreads();
        for (int off = 128; off; off >>= 1) {
            if (threadIdx.x < off) {
                float s = rs[threadIdx.x + off]; int i = ri[threadIdx.x + off];
                if (s < rs[threadIdx.x] || (s == rs[threadIdx.x] && i < ri[threadIdx.x])) {
                    rs[threadIdx.x] = s; ri[threadIdx.x] = i;
                }
            }
            __syncthreads();
        }
        if (threadIdx.x == 0) out[q] = ri[0];
    }
}

// ================= fallback: validated round-1 fp32 path =================
#define BM 128
#define BN 128
#define PAD 68

__global__ __launch_bounds__(256) void vq_fp32(
    const float4* __restrict__ lat, const float4* __restrict__ cb,
    const float* __restrict__ c2, int ktPer,
    int* __restrict__ outIdx, float* __restrict__ partS, int* __restrict__ partI,
    int writePartial) {
    __shared__ float As[BM][PAD];
    __shared__ float Bs[BN][PAD];
    __shared__ float c2s[BN];
    const int tid = threadIdx.x;
    const int tx = tid & 15;
    const int ty = tid >> 4;
    const int nBase = blockIdx.x * BM;
    const int kt0 = blockIdx.y * ktPer;
    const int ktN = kt0 + ktPer;
#pragma unroll
    for (int r = 0; r < 8; ++r) {
        int f = tid + 256 * r;
        int mm = f >> 4, d4 = f & 15;
        float4 v = lat[(size_t)(nBase + mm) * 16 + d4];
        *(float4*)&As[mm][d4 * 4] = v;
    }
    float best[8]; int bidx[8];
#pragma unroll
    for (int ii = 0; ii < 8; ++ii) { best[ii] = 3e38f; bidx[ii] = 0; }
    for (int kt = kt0; kt < ktN; ++kt) {
        const int kbase = kt * BN;
        __syncthreads();
#pragma unroll
        for (int r = 0; r < 8; ++r) {
            int f = tid + 256 * r;
            int k = f >> 4, d4 = f & 15;
            float4 v = cb[(size_t)(kbase + k) * 16 + d4];
            *(float4*)&Bs[k][d4 * 4] = v;
        }
        if (tid < BN) c2s[tid] = c2[kbase + tid];
        __syncthreads();
        float acc[8][8];
#pragma unroll
        for (int ii = 0; ii < 8; ++ii)
#pragma unroll
            for (int jj = 0; jj < 8; ++jj) acc[ii][jj] = 0.f;
#pragma unroll 4
        for (int d4 = 0; d4 < 16; ++d4) {
            float4 a[8], b[8];
#pragma unroll
            for (int ii = 0; ii < 8; ++ii) a[ii] = *(const float4*)&As[tx + 16 * ii][d4 * 4];
#pragma unroll
            for (int jj = 0; jj < 8; ++jj) b[jj] = *(const float4*)&Bs[ty + 16 * jj][d4 * 4];
#pragma unroll
            for (int ii = 0; ii < 8; ++ii)
#pragma unroll
                for (int jj = 0; jj < 8; ++jj)
                    acc[ii][jj] += a[ii].x * b[jj].x + a[ii].y * b[jj].y
                                 + a[ii].z * b[jj].z + a[ii].w * b[jj].w;
        }
#pragma unroll
        for (int jj = 0; jj < 8; ++jj) {
            int k = kbase + ty + 16 * jj;
            float cc = c2s[ty + 16 * jj];
#pragma unroll
            for (int ii = 0; ii < 8; ++ii) {
                float s = cc - 2.f * acc[ii][jj];
                if (s < best[ii]) { best[ii] = s; bidx[ii] = k; }
            }
        }
    }
    __syncthreads();
    float* redS = &As[0][0];
    int*   redI = (int*)&Bs[0][0];
#pragma unroll
    for (int ii = 0; ii < 8; ++ii) {
        int mm = tx + 16 * ii;
        redS[ty * BM + mm] = best[ii];
        redI[ty * BM + mm] = bidx[ii];
    }
    __syncthreads();
    if (tid < BM) {
        int mm = tid;
        float bs = redS[mm]; int bi = redI[mm];
#pragma unroll
        for (int t = 1; t < 16; ++t) {
            float s = redS[t * BM + mm]; int i = redI[t * BM + mm];
            if (s < bs || (s == bs && i < bi)) { bs = s; bi = i; }
        }
        int n = nBase + mm;
        if (writePartial) { partS[blockIdx.y * N_TOTAL + n] = bs; partI[blockIdx.y * N_TOTAL + n] = bi; }
        else outIdx[n] = bi;
    }
}

__global__ void vq_merge_fb(const float* __restrict__ partS, const int* __restrict__ partI,
                            int* __restrict__ out) {
    int n = blockIdx.x * 256 + threadIdx.x;
    float s0 = partS[n], s1 = partS[N_TOTAL + n];
    int   i0 = partI[n], i1 = partI[N_TOTAL + n];
    out[n] = (s1 < s0) ? i1 : i0;
}

extern "C" void kernel_launch(void* const* d_in, const int* in_sizes, int n_in,
                              void* d_out, int out_size, void* d_ws, size_t ws_size,
                              hipStream_t stream) {
    const float4* lat = (const float4*)d_in[0];
    const float4* cb  = (const float4*)d_in[1];
    int* out = (int*)d_out;
    char* ws = (char*)d_ws;

    if (ws_size >= WS_NEED) {
        float* c2   = (float*)(ws + O_C2);
        uint4* cbSw = (uint4*)(ws + O_CBSW);
        uint4* latSw= (uint4*)(ws + O_LATSW);
        float* pS1  = (float*)(ws + O_PS1);
        float* pS2  = (float*)(ws + O_PS2);
        int*   pI1  = (int*)(ws + O_PI1);
        int*   cnt  = (int*)(ws + O_CNT);
        int*   list = (int*)(ws + O_LIST);

        vq_norms<<<128, 256, 0, stream>>>(cb, c2, cnt);
        vq_split<<<1024, 256, 0, stream>>>(lat, latSw);
        vq_split<<<256, 256, 0, stream>>>(cb, cbSw);
        vq_mfma<<<dim3(256, 2), 256, 0, stream>>>(latSw, cbSw, c2, pS1, pS2, pI1);
        vq_merge2<<<128, 256, 0, stream>>>(pS1, pS2, pI1, out, cnt, list);
        vq_exact<<<256, 256, 0, stream>>>(lat, cb, c2, cnt, list, out);
    } else {
        float* c2 = (float*)ws;
        int* cntDummy = (int*)(ws + 32768 - 16);
        vq_norms<<<128, 256, 0, stream>>>(cb, c2, cntDummy);
        const size_t needSplit = 32768u + 2u * N_TOTAL * 4u + 2u * N_TOTAL * 4u + 64u;
        if (ws_size >= needSplit) {
            float* partS = (float*)(ws + 32768);
            int*   partI = (int*)(ws + 32768 + 2 * N_TOTAL * 4);
            dim3 grid(N_TOTAL / BM, 2);
            vq_fp32<<<grid, 256, 0, stream>>>(lat, cb, c2, (K_CODES / BN) / 2, out, partS, partI, 1);
            vq_merge_fb<<<N_TOTAL / 256, 256, 0, stream>>>(partS, partI, out);
        } else {
            dim3 grid(N_TOTAL / BM, 1);
            vq_fp32<<<grid, 256, 0, stream>>>(lat, cb, c2, K_CODES / BN, out, nullptr, nullptr, 0);
        }
    }
}

// Round 3
// 249.206 us; speedup vs baseline: 2.2888x; 1.4731x over previous
//
#include <hip/hip_runtime.h>
#include <stdint.h>

// VQ-VAE nearest-codebook index: N=32768 queries, D=64, K=8192 codes.
// Phase A: bf16x3 MFMA (hi/lo split) approx scores + per-query best/second-best.
// Certified error bound: per-score |err| <= E ~ 7.5e-3 worst case; queries with
// (s2 - s1) < EPS_GAP = 2E are re-solved exactly in fp32 (phase B), now via
// wave-parallel chunks + packed u64 atomicMin. Fallback: round-1 fp32 kernel.

#define N_TOTAL 32768
#define K_CODES 8192
#define EPS_GAP 0.015f

typedef __attribute__((ext_vector_type(16))) float  floatx16;
typedef __attribute__((ext_vector_type(8)))  __bf16 bf16x8;

// ---- workspace layout (bytes) ----
#define O_C2    0u          // 8192 f32
#define O_CBSW  32768u      // [256 kBlk][16 cg][32 m][8 bf16] = 2 MB
#define O_LATSW 2129920u    // [1024 qBlk][16 cg][32 m][8 bf16] = 8 MB
#define O_PS1   10518528u   // 2*32768 f32
#define O_PS2   10780672u
#define O_PI1   11042816u
#define O_CNT   11304960u
#define O_LIST  11305216u   // 32768 int
#define O_SLOT  11436288u   // 32768 u64
#define WS_NEED 11698432u

__device__ __forceinline__ unsigned int fkey(float s) {
    unsigned int u = __float_as_uint(s);
    return (u & 0x80000000u) ? ~u : (u | 0x80000000u);
}

// ---- codebook squared norms + zero flag counter ----
__global__ void vq_norms(const float4* __restrict__ cb, float* __restrict__ c2,
                         int* __restrict__ cnt) {
    if (blockIdx.x == 0 && threadIdx.x == 0) *cnt = 0;
    int t = blockIdx.x * 256 + threadIdx.x;
    int r = t >> 2, p = t & 3;
    float s = 0.f;
#pragma unroll
    for (int i = 0; i < 4; ++i) {
        float4 v = cb[r * 16 + p * 4 + i];
        s += v.x * v.x + v.y * v.y + v.z * v.z + v.w * v.w;
    }
    s += __shfl_xor(s, 1);
    s += __shfl_xor(s, 2);
    if (p == 0) c2[r] = s;
}

// ---- split fp32 rows into hi/lo bf16, MFMA-fragment layout ----
__global__ void vq_split(const float4* __restrict__ src, uint4* __restrict__ dst) {
    const int m = threadIdx.x & 31, g = threadIdx.x >> 5;
    const int rb = blockIdx.x;
    float4 a = src[(size_t)(rb * 32 + m) * 16 + g * 2];
    float4 b = src[(size_t)(rb * 32 + m) * 16 + g * 2 + 1];
    float x[8] = {a.x, a.y, a.z, a.w, b.x, b.y, b.z, b.w};
    bf16x8 hv, lv;
#pragma unroll
    for (int i = 0; i < 8; ++i) {
        float v  = x[i];
        __bf16 hb = (__bf16)v;           // RNE
        float r  = v - (float)hb;
        hv[i] = hb;
        lv[i] = (__bf16)r;
    }
    dst[(size_t)rb * 512 + g * 32 + m]       = __builtin_bit_cast(uint4, hv);
    dst[(size_t)rb * 512 + (8 + g) * 32 + m] = __builtin_bit_cast(uint4, lv);
}

// ---- phase A: 128 queries x 4096 codes per block (split-K=2) ----
__global__ __launch_bounds__(256, 2) void vq_mfma(
    const uint4* __restrict__ latSw, const uint4* __restrict__ cbSw,
    const float* __restrict__ c2,
    float* __restrict__ pS1, float* __restrict__ pS2, int* __restrict__ pI1) {
    __shared__ uint4 As[2048];   // 32 KB
    __shared__ uint4 Bs[2048];   // 32 KB
    const int tid = threadIdx.x;
    const int wr = tid >> 6, lane = tid & 63;
    const int m = lane & 31, h = lane >> 5;

#pragma unroll
    for (int i = 0; i < 8; ++i)
        As[tid + 256 * i] = latSw[(size_t)blockIdx.x * 2048 + tid + 256 * i];
    __syncthreads();

    bf16x8 aH[4], aL[4];
#pragma unroll
    for (int c = 0; c < 4; ++c) {
        aH[c] = __builtin_bit_cast(bf16x8, As[wr * 512 + (c * 2 + h) * 32 + m]);
        aL[c] = __builtin_bit_cast(bf16x8, As[wr * 512 + (8 + c * 2 + h) * 32 + m]);
    }

    float s1[16], s2[16]; int i1[16];
#pragma unroll
    for (int r = 0; r < 16; ++r) { s1[r] = 3e38f; s2[r] = 3e38f; i1[r] = 0; }

    const int kBase = blockIdx.y * 4096;
    const uint4* cbBase = cbSw + (size_t)kBase * 16;

    for (int stage = 0; stage < 32; ++stage) {
        __syncthreads();
#pragma unroll
        for (int i = 0; i < 8; ++i)
            Bs[tid + 256 * i] = cbBase[(size_t)stage * 2048 + tid + 256 * i];
        __syncthreads();

#pragma unroll
        for (int kb = 0; kb < 4; ++kb) {
            const int col = kBase + stage * 128 + kb * 32 + m;
            const float cc = c2[col];
            floatx16 acc;
#pragma unroll
            for (int r = 0; r < 16; ++r) acc[r] = 0.f;
#pragma unroll
            for (int c = 0; c < 4; ++c) {
                bf16x8 bH = __builtin_bit_cast(bf16x8, Bs[kb * 512 + (c * 2 + h) * 32 + m]);
                bf16x8 bL = __builtin_bit_cast(bf16x8, Bs[kb * 512 + (8 + c * 2 + h) * 32 + m]);
                acc = __builtin_amdgcn_mfma_f32_32x32x16_bf16(aH[c], bH, acc, 0, 0, 0);
                acc = __builtin_amdgcn_mfma_f32_32x32x16_bf16(aL[c], bH, acc, 0, 0, 0);
                acc = __builtin_amdgcn_mfma_f32_32x32x16_bf16(aH[c], bL, acc, 0, 0, 0);
            }
#pragma unroll
            for (int r = 0; r < 16; ++r) {
                float s = fmaf(-2.f, acc[r], cc);
                s2[r] = fminf(s2[r], fmaxf(s, s1[r]));
                bool lt = s < s1[r];
                i1[r] = lt ? col : i1[r];
                s1[r] = lt ? s : s1[r];
            }
        }
    }

#pragma unroll
    for (int mask = 1; mask <= 16; mask <<= 1) {
#pragma unroll
        for (int r = 0; r < 16; ++r) {
            float o1 = __shfl_xor(s1[r], mask);
            float o2 = __shfl_xor(s2[r], mask);
            int   oi = __shfl_xor(i1[r], mask);
            float n2 = fminf(fminf(s2[r], o2), fmaxf(s1[r], o1));
            bool take = (o1 < s1[r]) || (o1 == s1[r] && oi < i1[r]);
            s1[r] = take ? o1 : s1[r];
            i1[r] = take ? oi : i1[r];
            s2[r] = n2;
        }
    }

    if (m == 0) {
        const int qb = blockIdx.x * 128 + wr * 32;
        const int o0 = blockIdx.y * N_TOTAL;
#pragma unroll
        for (int r = 0; r < 16; ++r) {
            int row = (r & 3) + 8 * (r >> 2) + 4 * h;
            int q = qb + row;
            pS1[o0 + q] = s1[r];
            pS2[o0 + q] = s2[r];
            pI1[o0 + q] = i1[r];
        }
    }
}

// ---- merge split-K halves, write indices, flag near-ties, init slots ----
__global__ void vq_merge2(const float* __restrict__ pS1, const float* __restrict__ pS2,
                          const int* __restrict__ pI1, int* __restrict__ out,
                          int* __restrict__ cnt, int* __restrict__ list,
                          unsigned long long* __restrict__ slot) {
    int q = blockIdx.x * 256 + threadIdx.x;
    float a1 = pS1[q],           a2 = pS2[q];           int ai = pI1[q];
    float b1 = pS1[N_TOTAL + q], b2 = pS2[N_TOTAL + q]; int bi = pI1[N_TOTAL + q];
    bool take = (b1 < a1) || (b1 == a1 && bi < ai);
    float s1 = take ? b1 : a1;
    int   i1 = take ? bi : ai;
    float s2 = fminf(fminf(a2, b2), fmaxf(a1, b1));
    out[q] = i1;
    if (s2 - s1 < EPS_GAP) {
        int e = atomicAdd(cnt, 1);
        list[e] = q;
        slot[e] = 0xFFFFFFFFFFFFFFFFull;
    }
}

// ---- phase B: exact fp32, wave-parallel (query x 1024-code chunk) ----
__global__ __launch_bounds__(256) void vq_exact2(
    const float4* __restrict__ lat, const float4* __restrict__ cb,
    const float* __restrict__ c2, const int* __restrict__ cnt,
    const int* __restrict__ list, unsigned long long* __restrict__ slot) {
    __shared__ float qv[4][64];
    const int n = *cnt;
    const int totalChunks = n * 8;
    const int wInB = threadIdx.x >> 6;
    const int lane = threadIdx.x & 63;

    for (int base = blockIdx.x * 4; base < totalChunks; base += gridDim.x * 4) {
        const int c = base + wInB;
        const bool act = c < totalChunks;
        int e = 0, q = 0, kb = 0;
        if (act) { e = c >> 3; q = list[e]; kb = (c & 7) << 10; }
        __syncthreads();
        if (act && lane < 16) {
            float4 v = lat[(size_t)q * 16 + lane];
            *(float4*)&qv[wInB][lane * 4] = v;
        }
        __syncthreads();
        if (act) {
            float best = 3e38f; int bi = 0;
#pragma unroll 2
            for (int i = 0; i < 16; ++i) {
                const int k = kb + i * 64 + lane;
                float dot = 0.f;
#pragma unroll
                for (int d4 = 0; d4 < 16; ++d4) {
                    float4 cv = cb[(size_t)k * 16 + d4];
                    dot += qv[wInB][d4 * 4 + 0] * cv.x + qv[wInB][d4 * 4 + 1] * cv.y
                         + qv[wInB][d4 * 4 + 2] * cv.z + qv[wInB][d4 * 4 + 3] * cv.w;
                }
                float s = c2[k] - 2.f * dot;
                if (s < best) { best = s; bi = k; }
            }
            unsigned long long p = ((unsigned long long)fkey(best) << 32) | (unsigned)bi;
#pragma unroll
            for (int mask = 1; mask <= 32; mask <<= 1) {
                unsigned long long o = __shfl_xor(p, mask);
                p = o < p ? o : p;
            }
            if (lane == 0) atomicMin(&slot[e], p);
        }
    }
}

// ---- write back exact answers for flagged queries ----
__global__ void vq_write(const int* __restrict__ cnt, const int* __restrict__ list,
                         const unsigned long long* __restrict__ slot,
                         int* __restrict__ out) {
    int t = blockIdx.x * 256 + threadIdx.x;
    if (t < *cnt) out[list[t]] = (int)(slot[t] & 0xFFFFFFFFull);
}

// ================= fallback: validated round-1 fp32 path =================
#define BM 128
#define BN 128
#define PAD 68

__global__ __launch_bounds__(256) void vq_fp32(
    const float4* __restrict__ lat, const float4* __restrict__ cb,
    const float* __restrict__ c2, int ktPer,
    int* __restrict__ outIdx, float* __restrict__ partS, int* __restrict__ partI,
    int writePartial) {
    __shared__ float As[BM][PAD];
    __shared__ float Bs[BN][PAD];
    __shared__ float c2s[BN];
    const int tid = threadIdx.x;
    const int tx = tid & 15;
    const int ty = tid >> 4;
    const int nBase = blockIdx.x * BM;
    const int kt0 = blockIdx.y * ktPer;
    const int ktN = kt0 + ktPer;
#pragma unroll
    for (int r = 0; r < 8; ++r) {
        int f = tid + 256 * r;
        int mm = f >> 4, d4 = f & 15;
        float4 v = lat[(size_t)(nBase + mm) * 16 + d4];
        *(float4*)&As[mm][d4 * 4] = v;
    }
    float best[8]; int bidx[8];
#pragma unroll
    for (int ii = 0; ii < 8; ++ii) { best[ii] = 3e38f; bidx[ii] = 0; }
    for (int kt = kt0; kt < ktN; ++kt) {
        const int kbase = kt * BN;
        __syncthreads();
#pragma unroll
        for (int r = 0; r < 8; ++r) {
            int f = tid + 256 * r;
            int k = f >> 4, d4 = f & 15;
            float4 v = cb[(size_t)(kbase + k) * 16 + d4];
            *(float4*)&Bs[k][d4 * 4] = v;
        }
        if (tid < BN) c2s[tid] = c2[kbase + tid];
        __syncthreads();
        float acc[8][8];
#pragma unroll
        for (int ii = 0; ii < 8; ++ii)
#pragma unroll
            for (int jj = 0; jj < 8; ++jj) acc[ii][jj] = 0.f;
#pragma unroll 4
        for (int d4 = 0; d4 < 16; ++d4) {
            float4 a[8], b[8];
#pragma unroll
            for (int ii = 0; ii < 8; ++ii) a[ii] = *(const float4*)&As[tx + 16 * ii][d4 * 4];
#pragma unroll
            for (int jj = 0; jj < 8; ++jj) b[jj] = *(const float4*)&Bs[ty + 16 * jj][d4 * 4];
#pragma unroll
            for (int ii = 0; ii < 8; ++ii)
#pragma unroll
                for (int jj = 0; jj < 8; ++jj)
                    acc[ii][jj] += a[ii].x * b[jj].x + a[ii].y * b[jj].y
                                 + a[ii].z * b[jj].z + a[ii].w * b[jj].w;
        }
#pragma unroll
        for (int jj = 0; jj < 8; ++jj) {
            int k = kbase + ty + 16 * jj;
            float cc = c2s[ty + 16 * jj];
#pragma unroll
            for (int ii = 0; ii < 8; ++ii) {
                float s = cc - 2.f * acc[ii][jj];
                if (s < best[ii]) { best[ii] = s; bidx[ii] = k; }
            }
        }
    }
    __syncthreads();
    float* redS = &As[0][0];
    int*   redI = (int*)&Bs[0][0];
#pragma unroll
    for (int ii = 0; ii < 8; ++ii) {
        int mm = tx + 16 * ii;
        redS[ty * BM + mm] = best[ii];
        redI[ty * BM + mm] = bidx[ii];
    }
    __syncthreads();
    if (tid < BM) {
        int mm = tid;
        float bs = redS[mm]; int bi = redI[mm];
#pragma unroll
        for (int t = 1; t < 16; ++t) {
            float s = redS[t * BM + mm]; int i = redI[t * BM + mm];
            if (s < bs || (s == bs && i < bi)) { bs = s; bi = i; }
        }
        int n = nBase + mm;
        if (writePartial) { partS[blockIdx.y * N_TOTAL + n] = bs; partI[blockIdx.y * N_TOTAL + n] = bi; }
        else outIdx[n] = bi;
    }
}

__global__ void vq_merge_fb(const float* __restrict__ partS, const int* __restrict__ partI,
                            int* __restrict__ out) {
    int n = blockIdx.x * 256 + threadIdx.x;
    float s0 = partS[n], s1 = partS[N_TOTAL + n];
    int   i0 = partI[n], i1 = partI[N_TOTAL + n];
    out[n] = (s1 < s0) ? i1 : i0;
}

extern "C" void kernel_launch(void* const* d_in, const int* in_sizes, int n_in,
                              void* d_out, int out_size, void* d_ws, size_t ws_size,
                              hipStream_t stream) {
    const float4* lat = (const float4*)d_in[0];
    const float4* cb  = (const float4*)d_in[1];
    int* out = (int*)d_out;
    char* ws = (char*)d_ws;

    if (ws_size >= WS_NEED) {
        float* c2   = (float*)(ws + O_C2);
        uint4* cbSw = (uint4*)(ws + O_CBSW);
        uint4* latSw= (uint4*)(ws + O_LATSW);
        float* pS1  = (float*)(ws + O_PS1);
        float* pS2  = (float*)(ws + O_PS2);
        int*   pI1  = (int*)(ws + O_PI1);
        int*   cnt  = (int*)(ws + O_CNT);
        int*   list = (int*)(ws + O_LIST);
        unsigned long long* slot = (unsigned long long*)(ws + O_SLOT);

        vq_norms<<<128, 256, 0, stream>>>(cb, c2, cnt);
        vq_split<<<1024, 256, 0, stream>>>(lat, latSw);
        vq_split<<<256, 256, 0, stream>>>(cb, cbSw);
        vq_mfma<<<dim3(256, 2), 256, 0, stream>>>(latSw, cbSw, c2, pS1, pS2, pI1);
        vq_merge2<<<128, 256, 0, stream>>>(pS1, pS2, pI1, out, cnt, list, slot);
        vq_exact2<<<1024, 256, 0, stream>>>(lat, cb, c2, cnt, list, slot);
        vq_write<<<128, 256, 0, stream>>>(cnt, list, slot, out);
    } else {
        float* c2 = (float*)ws;
        int* cntDummy = (int*)(ws + 32768 - 16);
        vq_norms<<<128, 256, 0, stream>>>(cb, c2, cntDummy);
        const size_t needSplit = 32768u + 2u * N_TOTAL * 4u + 2u * N_TOTAL * 4u + 64u;
        if (ws_size >= needSplit) {
            float* partS = (float*)(ws + 32768);
            int*   partI = (int*)(ws + 32768 + 2 * N_TOTAL * 4);
            dim3 grid(N_TOTAL / BM, 2);
            vq_fp32<<<grid, 256, 0, stream>>>(lat, cb, c2, (K_CODES / BN) / 2, out, partS, partI, 1);
            vq_merge_fb<<<N_TOTAL / 256, 256, 0, stream>>>(partS, partI, out);
        } else {
            dim3 grid(N_TOTAL / BM, 1);
            vq_fp32<<<grid, 256, 0, stream>>>(lat, cb, c2, K_CODES / BN, out, nullptr, nullptr, 0);
        }
    }
}